// Round 9
// baseline (395.377 us; speedup 1.0000x reference)
//
#include <hip/hip_runtime.h>
#include <hip/hip_bf16.h>
#include <math.h>
#include <stdint.h>

#define B 2
#define H 16
#define L 2048
#define D 64
#define NB 32

typedef unsigned short u16;
typedef unsigned int u32;
typedef __attribute__((ext_vector_type(2))) unsigned int u32x2;
typedef __attribute__((ext_vector_type(4))) unsigned int u32x4;
typedef __attribute__((ext_vector_type(8))) short s16x8;
typedef __attribute__((ext_vector_type(4))) float f32x4;

union FragU { s16x8 v; u32 u[4]; };

__device__ __forceinline__ u32 pkbf(float a, float b) {
  __hip_bfloat162 h = __float22bfloat162_rn(make_float2(a, b));  // v_cvt_pk_bf16_f32
  union { __hip_bfloat162 h; u32 u; } cv; cv.h = h; return cv.u;
}
__device__ __forceinline__ float bf2f(u32 u16bits) {
  union { u32 u; float f; } c; c.u = u16bits << 16; return c.f;
}
// split float4 -> packed hi (u32x2) + lo (u32x2), RNE both levels
__device__ __forceinline__ void split4(float4 p, u32x2& hi, u32x2& lo) {
  u32 h01 = pkbf(p.x, p.y), h23 = pkbf(p.z, p.w);
  float rx = p.x - bf2f(h01 & 0xffffu);
  float ry = p.y - bf2f(h01 >> 16);
  float rz = p.z - bf2f(h23 & 0xffffu);
  float rw = p.w - bf2f(h23 >> 16);
  hi = (u32x2){h01, h23};
  lo = (u32x2){pkbf(rx, ry), pkbf(rz, rw)};
}
// XOR-swizzled byte offset in a [64][128B] tile: 2 lanes/bank (free) for the
// fixed-col/varying-row ds_read_b128 / 8B-store pattern (guide §6 G4).
__device__ __forceinline__ int swz(int row, int colb) {
  return (row << 7) + (colb ^ ((row & 7) << 4));
}

// ---------------------------------------------------------------------------
// k_prep: single pass over K (split + column sums fused), V transpose split.
// 16 B stores on all four bf16 planes. Per-(bh,j) max ||k_row||^2.
// ---------------------------------------------------------------------------
__global__ __launch_bounds__(256) void k_prep(const float* __restrict__ k,
                                              const float* __restrict__ v,
                                              float* __restrict__ ksum,
                                              u16* __restrict__ khi_g,
                                              u16* __restrict__ klo_g,
                                              u16* __restrict__ vthi_g,
                                              u16* __restrict__ vtlo_g,
                                              float* __restrict__ kbmax) {
  int blk = blockIdx.x, bh = blk >> 5, j = blk & 31, t = threadIdx.x;
  int lane = t & 63, w = t >> 6;
  __shared__ float vt[64 * 65];
  __shared__ float pk_[4][64];
  __shared__ unsigned bmaxS;
  if (t == 0) bmaxS = 0u;
  size_t base = (size_t)blk * 4096;

  int r0 = t >> 3;          // 0..31
  int c8 = (t & 7) * 8;     // 0..56
  float cs[8] = {0.f, 0.f, 0.f, 0.f, 0.f, 0.f, 0.f, 0.f};
  float rmax = 0.f;
#pragma unroll
  for (int it = 0; it < 2; ++it) {
    int r = r0 + 32 * it;
    const float* kp = k + base + r * 64 + c8;
    float4 f0 = *(const float4*)kp;
    float4 f1 = *(const float4*)(kp + 4);
    u32x2 h0, l0, h1, l1;
    split4(f0, h0, l0); split4(f1, h1, l1);
    *(u32x4*)(khi_g + base + r * 64 + c8) = (u32x4){h0[0], h0[1], h1[0], h1[1]};
    *(u32x4*)(klo_g + base + r * 64 + c8) = (u32x4){l0[0], l0[1], l1[0], l1[1]};
    cs[0] += f0.x; cs[1] += f0.y; cs[2] += f0.z; cs[3] += f0.w;
    cs[4] += f1.x; cs[5] += f1.y; cs[6] += f1.z; cs[7] += f1.w;
    float ssq = f0.x*f0.x + f0.y*f0.y + f0.z*f0.z + f0.w*f0.w
              + f1.x*f1.x + f1.y*f1.y + f1.z*f1.z + f1.w*f1.w;
    ssq += __shfl_xor(ssq, 1); ssq += __shfl_xor(ssq, 2); ssq += __shfl_xor(ssq, 4);
    if ((t & 7) == 0) rmax = fmaxf(rmax, ssq);
    const float* vp = v + base + r * 64 + c8;
    float4 g0 = *(const float4*)vp;
    float4 g1 = *(const float4*)(vp + 4);
    vt[(c8 + 0) * 65 + r] = g0.x;
    vt[(c8 + 1) * 65 + r] = g0.y;
    vt[(c8 + 2) * 65 + r] = g0.z;
    vt[(c8 + 3) * 65 + r] = g0.w;
    vt[(c8 + 4) * 65 + r] = g1.x;
    vt[(c8 + 5) * 65 + r] = g1.y;
    vt[(c8 + 6) * 65 + r] = g1.z;
    vt[(c8 + 7) * 65 + r] = g1.w;
  }
  if ((t & 7) == 0) atomicMax(&bmaxS, __float_as_uint(rmax));
  // column-sum reduce over r-groups: xor 8/16/32 keep lane&7 (the column group)
#pragma unroll
  for (int i = 0; i < 8; ++i) {
    cs[i] += __shfl_xor(cs[i], 8);
    cs[i] += __shfl_xor(cs[i], 16);
    cs[i] += __shfl_xor(cs[i], 32);
  }
  if (lane < 8) {
    *(float4*)&pk_[w][lane * 8]     = (float4){cs[0], cs[1], cs[2], cs[3]};
    *(float4*)&pk_[w][lane * 8 + 4] = (float4){cs[4], cs[5], cs[6], cs[7]};
  }
  __syncthreads();
  if (t < 64) ksum[(size_t)blk * 64 + t] = pk_[0][t] + pk_[1][t] + pk_[2][t] + pk_[3][t];
  if (t == 0) kbmax[blk] = __uint_as_float(bmaxS);
#pragma unroll
  for (int it = 0; it < 2; ++it) {
    int idx = t + 256 * it, d = idx >> 3, s8 = (idx & 7) * 8;
    const float* vr = &vt[d * 65 + s8];
    float4 f0 = {vr[0], vr[1], vr[2], vr[3]};
    float4 f1 = {vr[4], vr[5], vr[6], vr[7]};
    u32x2 h0, l0, h1, l1;
    split4(f0, h0, l0); split4(f1, h1, l1);
    size_t o = (size_t)bh * 131072 + (size_t)d * 2048 + j * 64 + s8;
    *(u32x4*)(vthi_g + o) = (u32x4){h0[0], h0[1], h1[0], h1[1]};
    *(u32x4*)(vtlo_g + o) = (u32x4){l0[0], l0[1], l1[0], l1[1]};
  }
}

// ---------------------------------------------------------------------------
// k_attn: round-1 body (best verified: 2 q-blocks/WG, union-mask K sweep,
// cooperative loads, no spills) + the two R5-proven fixes:
//  (1) P tiles XOR-swizzled [64][128B] planes -> bank conflicts ~free
//  (2) rbm/lpart/qm/MS/linv OVERLAID into the P region (dead before the
//      first P write) -> LDS 57.9 KB -> 32.8 KB -> 3 WGs/CU at (256,3).
// LDS map (bytes), total 32800:
//   P planes: qb0 hi @0, qb0 lo @8192, qb1 hi @16384, qb1 lo @24576
//   overlay (dead before Pass B): rbm u32[2*64*33] @0 (16896),
//     lpart f32[4][128] @16896, qm f32[2][64] @18944, MS @19456, linv @19968
//   flg @32768
// ---------------------------------------------------------------------------
__global__ __launch_bounds__(256, 3) void k_attn(
    const float* __restrict__ q,
    const float* __restrict__ ksum,
    const u16* __restrict__ khi_g, const u16* __restrict__ klo_g,
    const u16* __restrict__ vthi_g, const u16* __restrict__ vtlo_g,
    const float* __restrict__ cdfthreshd, const float* __restrict__ simthreshd1,
    const float* __restrict__ pvthreshd, const float* __restrict__ kbmax,
    float* __restrict__ out) {
  int blk0 = blockIdx.x;
  int blk = (blk0 & 7) * 64 + (blk0 >> 3);   // bijective: 512 % 8 == 0
  int bh = blk >> 4, ip = blk & 15, h = bh & (H - 1);
  int t = threadIdx.x, lane = t & 63, w = t >> 6;
  int m16 = lane & 15, quad = lane >> 4;

  __shared__ __align__(16) uint8_t smem[32800];
  u32*   rbm0  = (u32*)smem;                    // overlay: [2][64][33] keys
  float* lpart = (float*)(smem + 16896);        // [4][128]
  float* qmS   = (float*)(smem + 18944);        // [2][64]
  float* MSs   = (float*)(smem + 19456);        // [2][64]
  float* linvS = (float*)(smem + 19968);        // [2][64]
  int*   flg   = (int*)(smem + 32768);          // [0..1] pooled, [2..3] mw, [4..5] gm, [6] kmax2
#define PHB(qb) (smem + (qb) * 16384)           // hi plane of q-block qb
#define PLB(qb) (smem + (qb) * 16384 + 8192)    // lo plane

  const float* qg0 = q + ((size_t)bh * L + (size_t)(2 * ip) * 64) * D;
  const float* qg1 = qg0 + 64 * D;
  const u16* kh = khi_g + (size_t)bh * (L * D);
  const u16* kl = klo_g + (size_t)bh * (L * D);
  const u16* vh = vthi_g + (size_t)bh * (L * D);
  const u16* vl = vtlo_g + (size_t)bh * (L * D);

  // ---- Q B-fragments from global (f32 -> split, registers) ----
  s16x8 qhf[2][4][2], qlf[2][4][2];
#pragma unroll
  for (int qb = 0; qb < 2; ++qb) {
    const float* qgq = qb ? qg1 : qg0;
#pragma unroll
    for (int nt = 0; nt < 4; ++nt)
#pragma unroll
      for (int ks = 0; ks < 2; ++ks) {
        const float* p0 = qgq + (16 * nt + m16) * 64 + ks * 32 + quad * 8;
        float4 a = *(const float4*)p0;
        float4 b2 = *(const float4*)(p0 + 4);
        u32x2 ha, la, hb, lb;
        split4(a, ha, la); split4(b2, hb, lb);
        FragU fh, fl;
        fh.u[0] = ha[0]; fh.u[1] = ha[1]; fh.u[2] = hb[0]; fh.u[3] = hb[1];
        fl.u[0] = la[0]; fl.u[1] = la[1]; fl.u[2] = lb[0]; fl.u[3] = lb[1];
        qhf[qb][nt][ks] = fh.v; qlf[qb][nt][ks] = fl.v;
      }
  }
  for (int e = t; e < 2 * 64 * 33; e += 256)
    rbm0[e] = 0x7F800000u;   // +inf keys (rbm0, rbm1 contiguous)

  // ---- phase 1: qm per qb (w0,w2), kmax2 (w1) ----
  if (w == 0 || w == 2) {
    int qb = w >> 1;
    const float* qgq = qb ? qg1 : qg0;
    float s = 0.f;
    for (int r = 0; r < 64; ++r) s += qgq[r * 64 + lane];
    qmS[qb * 64 + lane] = s * (1.f / 64.f);
  }
  if (w == 1) {
    float m = (lane < 32) ? kbmax[bh * 32 + lane] : 0.f;
    for (int off = 16; off; off >>= 1) m = fmaxf(m, __shfl_xor(m, off, 32));
    if (lane == 0) ((float*)flg)[6] = m;
  }
  __syncthreads();

  // ---- phase 2: CDF keep (w0:qb0, w2:qb1); pooled cos + M (w1:qb0, w3:qb1) ----
  bool keepj = false;
  if ((w == 0 || w == 2) && lane < 32) {
    int qb = w >> 1, j = lane;
    const float* qmv = qmS + qb * 64;
    const float* ksp = ksum + (size_t)bh * NB * 64 + j * 64;
    float sv = 0.f;
    for (int d = 0; d < 64; ++d) sv += qmv[d] * ksp[d];
    sv *= (1.f / 64.f) * 0.125f;
    float mx = sv;
    for (int off = 16; off; off >>= 1) mx = fmaxf(mx, __shfl_xor(mx, off, 32));
    float p = expf(sv - mx);
    float sum = p;
    for (int off = 16; off; off >>= 1) sum += __shfl_xor(sum, off, 32);
    p /= sum;
    float excl = 0.f;
    for (int u = 0; u < 32; ++u) {
      float pu = __shfl(p, u, 32);
      if ((pu > p) || (pu == p && u < j)) excl += pu;
    }
    keepj = excl < cdfthreshd[h];
  }
  if (w == 1 || w == 3) {
    int qb = w >> 1, r = lane;
    const float* qgq = qb ? qg1 : qg0;
    const float* qmv = qmS + qb * 64;
    float kmax2 = ((float*)flg)[6];
    float dot = 0.f, qn2 = 0.f, qmn2 = 0.f;
    for (int d = 0; d < 64; ++d) {
      float a = qgq[r * 64 + d], b2 = qmv[d];
      dot += a * b2; qn2 += a * a; qmn2 += b2 * b2;
    }
    float cs = dot / (sqrtf(qn2) * sqrtf(qmn2) + 1e-6f);
    float su = cs;
    for (int off = 32; off; off >>= 1) su += __shfl_xor(su, off);
    if (lane == 0) flg[qb] = (su * (1.f / 64.f)) > simthreshd1[h];
    MSs[qb * 64 + r] = sqrtf(qn2 * kmax2) * 0.125f;  // M_r >= |s| (Cauchy-Schwarz)
  }
  __syncthreads();
  if ((w == 0 || w == 2) && lane < 32) {
    int qb = w >> 1;
    bool bit = keepj || !flg[qb] || (lane == 0);
    unsigned long long bal = __ballot(bit);
    if (lane == 0) flg[2 + qb] = (int)(u32)bal;
  }
  __syncthreads();
  u32 mw0 = (u32)flg[2], mw1 = (u32)flg[3];

  float Mq[2][4];
#pragma unroll
  for (int qb = 0; qb < 2; ++qb)
#pragma unroll
    for (int nt = 0; nt < 4; ++nt) Mq[qb][nt] = MSs[qb * 64 + 16 * nt + m16];

  // ---- Pass A: union sweep, one K load serves both q-blocks ----
  float lp[2][4] = {{0.f,0.f,0.f,0.f},{0.f,0.f,0.f,0.f}};
  {
    u32 mwU = mw0 | mw1;
    int j = (int)__builtin_ctz(mwU);
    u32 rm_ = mwU & (mwU - 1);
    s16x8 ka[2][2], kan[2][2];
    {
      const u16* kr0 = kh + (size_t)(j * 64 + 16 * w + m16) * 64 + quad * 8;
      const u16* kl0 = kl + (size_t)(j * 64 + 16 * w + m16) * 64 + quad * 8;
#pragma unroll
      for (int ks = 0; ks < 2; ++ks) {
        ka[ks][0] = *(const s16x8*)(kr0 + ks * 32);
        ka[ks][1] = *(const s16x8*)(kl0 + ks * 32);
      }
    }
    for (;;) {
      int nj = -1;
      if (rm_) {
        nj = (int)__builtin_ctz(rm_); rm_ &= rm_ - 1;
        const u16* nr = kh + (size_t)(nj * 64 + 16 * w + m16) * 64 + quad * 8;
        const u16* nl = kl + (size_t)(nj * 64 + 16 * w + m16) * 64 + quad * 8;
#pragma unroll
        for (int ks = 0; ks < 2; ++ks) {
          kan[ks][0] = *(const s16x8*)(nr + ks * 32);
          kan[ks][1] = *(const s16x8*)(nl + ks * 32);
        }
      }
#pragma unroll
      for (int qb = 0; qb < 2; ++qb) {
        u32 mm = qb ? mw1 : mw0;
        if (!((mm >> j) & 1u)) continue;
        f32x4 acc[4];
#pragma unroll
        for (int nt = 0; nt < 4; ++nt) acc[nt] = (f32x4){0.f, 0.f, 0.f, 0.f};
        __builtin_amdgcn_s_setprio(1);
#pragma unroll
        for (int ks = 0; ks < 2; ++ks)
#pragma unroll
          for (int nt = 0; nt < 4; ++nt) {
            acc[nt] = __builtin_amdgcn_mfma_f32_16x16x32_bf16(ka[ks][0], qhf[qb][nt][ks], acc[nt], 0, 0, 0);
            acc[nt] = __builtin_amdgcn_mfma_f32_16x16x32_bf16(ka[ks][1], qhf[qb][nt][ks], acc[nt], 0, 0, 0);
            acc[nt] = __builtin_amdgcn_mfma_f32_16x16x32_bf16(ka[ks][0], qlf[qb][nt][ks], acc[nt], 0, 0, 0);
          }
        __builtin_amdgcn_s_setprio(0);
#pragma unroll
        for (int nt = 0; nt < 4; ++nt) {
          float vmax = -1e30f;
#pragma unroll
          for (int reg = 0; reg < 4; ++reg) {
            float s = acc[nt][reg] * 0.125f - Mq[qb][nt];
            lp[qb][nt] += __expf(s);
            vmax = fmaxf(vmax, s);
          }
          vmax = fmaxf(vmax, __shfl_xor(vmax, 16));
          vmax = fmaxf(vmax, __shfl_xor(vmax, 32));
          if (quad == 0)
            atomicMin(rbm0 + qb * (64 * 33) + (16 * nt + m16) * 33 + j,
                      __float_as_uint(fmaxf(-vmax, 0.f)));
        }
      }
      if (nj < 0) break;
#pragma unroll
      for (int ks = 0; ks < 2; ++ks) { ka[ks][0] = kan[ks][0]; ka[ks][1] = kan[ks][1]; }
      j = nj;
    }
  }
#pragma unroll
  for (int qb = 0; qb < 2; ++qb)
#pragma unroll
    for (int nt = 0; nt < 4; ++nt) {
      float s = lp[qb][nt];
      s += __shfl_xor(s, 16); s += __shfl_xor(s, 32);
      if (quad == 0) lpart[w * 128 + qb * 64 + 16 * nt + m16] = s;
    }
  __syncthreads();
  if (t < 128) linvS[t] = 1.f / (lpart[t] + lpart[128 + t] + lpart[256 + t] + lpart[384 + t]);
  __syncthreads();

  // ---- PV gate: wave0 -> qb0, wave1 -> qb1 ----
  if (w < 2 && lane < 32) {
    u32 mm = w ? mw1 : mw0;
    bool keep = (mm >> lane) & 1u;
    if (keep && lane != 0) {
      float thr = pvthreshd[h] * 1e-3f;
      const float* lin = linvS + w * 64;
      const u32* rb = rbm0 + w * (64 * 33);
      float mp = 0.f;
      for (int r = 0; r < 64; ++r) {
        float key = __uint_as_float(rb[r * 33 + lane]);
        mp = fmaxf(mp, __expf(-key) * lin[r]);
      }
      keep = mp >= thr;
    }
    unsigned long long bal = __ballot(keep);
    if (lane == 0) flg[4 + w] = (int)(u32)bal;
  }
  __syncthreads();
  u32 gm0 = (u32)flg[4], gm1 = (u32)flg[5];

  // ---- Pass B ----
  float linq[2][4];
#pragma unroll
  for (int qb = 0; qb < 2; ++qb)
#pragma unroll
    for (int nt = 0; nt < 4; ++nt) linq[qb][nt] = linvS[qb * 64 + 16 * nt + m16];
  f32x4 oacc[2][4];
#pragma unroll
  for (int qb = 0; qb < 2; ++qb)
#pragma unroll
    for (int nt = 0; nt < 4; ++nt) oacc[qb][nt] = (f32x4){0.f, 0.f, 0.f, 0.f};

  {
    u32 gmU = gm0 | gm1;
    int j = -1;
    u32 g2 = gmU;
    s16x8 ka[2][2];
    if (g2) {
      j = (int)__builtin_ctz(g2); g2 &= g2 - 1;
      const u16* kr0 = kh + (size_t)(j * 64 + 16 * w + m16) * 64 + quad * 8;
      const u16* kl0 = kl + (size_t)(j * 64 + 16 * w + m16) * 64 + quad * 8;
#pragma unroll
      for (int ks = 0; ks < 2; ++ks) {
        ka[ks][0] = *(const s16x8*)(kr0 + ks * 32);
        ka[ks][1] = *(const s16x8*)(kl0 + ks * 32);
      }
    }
    while (j >= 0) {
      int in0 = (gm0 >> j) & 1, in1 = (gm1 >> j) & 1;
      // V^T A-frags for current j (issued early, consumed late)
      s16x8 va[2][2];
      {
        const u16* vr0 = vh + (size_t)(16 * w + m16) * L + j * 64 + quad * 8;
        const u16* vl0 = vl + (size_t)(16 * w + m16) * L + j * 64 + quad * 8;
#pragma unroll
        for (int ks = 0; ks < 2; ++ks) {
          va[ks][0] = *(const s16x8*)(vr0 + ks * 32);
          va[ks][1] = *(const s16x8*)(vl0 + ks * 32);
        }
      }
      // S for qb0
      f32x4 acc[4];
      if (in0) {
#pragma unroll
        for (int nt = 0; nt < 4; ++nt) acc[nt] = (f32x4){0.f, 0.f, 0.f, 0.f};
        __builtin_amdgcn_s_setprio(1);
#pragma unroll
        for (int ks = 0; ks < 2; ++ks)
#pragma unroll
          for (int nt = 0; nt < 4; ++nt) {
            acc[nt] = __builtin_amdgcn_mfma_f32_16x16x32_bf16(ka[ks][0], qhf[0][nt][ks], acc[nt], 0, 0, 0);
            acc[nt] = __builtin_amdgcn_mfma_f32_16x16x32_bf16(ka[ks][1], qhf[0][nt][ks], acc[nt], 0, 0, 0);
            acc[nt] = __builtin_amdgcn_mfma_f32_16x16x32_bf16(ka[ks][0], qlf[0][nt][ks], acc[nt], 0, 0, 0);
          }
        __builtin_amdgcn_s_setprio(0);
      }
      __syncthreads();   // prior PV reads of P complete (also overlay reads, 1st iter)
      if (in0) {
#pragma unroll
        for (int nt = 0; nt < 4; ++nt) {
          float4 pv;
          pv.x = __expf(acc[nt][0] * 0.125f - Mq[0][nt]) * linq[0][nt];
          pv.y = __expf(acc[nt][1] * 0.125f - Mq[0][nt]) * linq[0][nt];
          pv.z = __expf(acc[nt][2] * 0.125f - Mq[0][nt]) * linq[0][nt];
          pv.w = __expf(acc[nt][3] * 0.125f - Mq[0][nt]) * linq[0][nt];
          u32x2 hi, lo; split4(pv, hi, lo);
          int off = swz(16 * nt + m16, 32 * w + 8 * quad);
          *(u32x2*)(PHB(0) + off) = hi;
          *(u32x2*)(PLB(0) + off) = lo;
        }
      }
      // S for qb1 (fills the barrier window), then P1 write
      if (in1) {
#pragma unroll
        for (int nt = 0; nt < 4; ++nt) acc[nt] = (f32x4){0.f, 0.f, 0.f, 0.f};
        __builtin_amdgcn_s_setprio(1);
#pragma unroll
        for (int ks = 0; ks < 2; ++ks)
#pragma unroll
          for (int nt = 0; nt < 4; ++nt) {
            acc[nt] = __builtin_amdgcn_mfma_f32_16x16x32_bf16(ka[ks][0], qhf[1][nt][ks], acc[nt], 0, 0, 0);
            acc[nt] = __builtin_amdgcn_mfma_f32_16x16x32_bf16(ka[ks][1], qhf[1][nt][ks], acc[nt], 0, 0, 0);
            acc[nt] = __builtin_amdgcn_mfma_f32_16x16x32_bf16(ka[ks][0], qlf[1][nt][ks], acc[nt], 0, 0, 0);
          }
        __builtin_amdgcn_s_setprio(0);
#pragma unroll
        for (int nt = 0; nt < 4; ++nt) {
          float4 pv;
          pv.x = __expf(acc[nt][0] * 0.125f - Mq[1][nt]) * linq[1][nt];
          pv.y = __expf(acc[nt][1] * 0.125f - Mq[1][nt]) * linq[1][nt];
          pv.z = __expf(acc[nt][2] * 0.125f - Mq[1][nt]) * linq[1][nt];
          pv.w = __expf(acc[nt][3] * 0.125f - Mq[1][nt]) * linq[1][nt];
          u32x2 hi, lo; split4(pv, hi, lo);
          int off = swz(16 * nt + m16, 32 * w + 8 * quad);
          *(u32x2*)(PHB(1) + off) = hi;
          *(u32x2*)(PLB(1) + off) = lo;
        }
      }
      // prefetch next K (ka fully consumed)
      int nj = -1;
      if (g2) {
        nj = (int)__builtin_ctz(g2); g2 &= g2 - 1;
        const u16* nr = kh + (size_t)(nj * 64 + 16 * w + m16) * 64 + quad * 8;
        const u16* nl = kl + (size_t)(nj * 64 + 16 * w + m16) * 64 + quad * 8;
#pragma unroll
        for (int ks = 0; ks < 2; ++ks) {
          ka[ks][0] = *(const s16x8*)(nr + ks * 32);
          ka[ks][1] = *(const s16x8*)(nl + ks * 32);
        }
      }
      __syncthreads();
      // PV for both q-blocks (va shared)
#pragma unroll
      for (int qb = 0; qb < 2; ++qb) {
        if (!(qb ? in1 : in0)) continue;
        const uint8_t* ph_ = PHB(qb);
        const uint8_t* pl_ = PLB(qb);
#pragma unroll
        for (int ks = 0; ks < 2; ++ks)
#pragma unroll
          for (int nt = 0; nt < 4; ++nt) {
            s16x8 pbh = *(const s16x8*)(ph_ + swz(16 * nt + m16, ks * 64 + quad * 16));
            s16x8 pbl = *(const s16x8*)(pl_ + swz(16 * nt + m16, ks * 64 + quad * 16));
            __builtin_amdgcn_s_setprio(1);
            oacc[qb][nt] = __builtin_amdgcn_mfma_f32_16x16x32_bf16(va[ks][0], pbh, oacc[qb][nt], 0, 0, 0);
            oacc[qb][nt] = __builtin_amdgcn_mfma_f32_16x16x32_bf16(va[ks][1], pbh, oacc[qb][nt], 0, 0, 0);
            oacc[qb][nt] = __builtin_amdgcn_mfma_f32_16x16x32_bf16(va[ks][0], pbl, oacc[qb][nt], 0, 0, 0);
            __builtin_amdgcn_s_setprio(0);
          }
      }
      j = nj;
    }
  }

  // ---- store O: lane holds q-row = 16nt+m16, d = 16w+4quad (f32x4) ----
#pragma unroll
  for (int qb = 0; qb < 2; ++qb) {
    float* ob = out + ((size_t)bh * L + (size_t)(2 * ip + qb) * 64) * D;
#pragma unroll
    for (int nt = 0; nt < 4; ++nt)
      *(f32x4*)(ob + (16 * nt + m16) * 64 + 16 * w + 4 * quad) = oacc[qb][nt];
  }
}

// ---------------------------------------------------------------------------
extern "C" void kernel_launch(void* const* d_in, const int* in_sizes, int n_in,
                              void* d_out, int out_size, void* d_ws, size_t ws_size,
                              hipStream_t stream) {
  (void)in_sizes; (void)n_in; (void)out_size; (void)ws_size;
  const float* q   = (const float*)d_in[0];
  const float* k   = (const float*)d_in[1];
  const float* v   = (const float*)d_in[2];
  const float* cdf = (const float*)d_in[3];
  const float* sim = (const float*)d_in[4];
  const float* pvt = (const float*)d_in[5];
  float* out = (float*)d_out;

  uint8_t* w8 = (uint8_t*)d_ws;
  float* ksum  = (float*)w8;                          // 1024*64 f (256 KB)
  float* kbmax = (float*)(w8 + 262144);               // 1024 f (4 KB)
  u16* khi_g  = (u16*)(w8 + 266240);                  // 4 planes x 8 MB
  u16* klo_g  = khi_g + (size_t)B * H * L * D;
  u16* vthi_g = klo_g + (size_t)B * H * L * D;
  u16* vtlo_g = vthi_g + (size_t)B * H * L * D;

  k_prep<<<B * H * NB, 256, 0, stream>>>(k, v, ksum, khi_g, klo_g, vthi_g, vtlo_g, kbmax);
  k_attn<<<B * H * NB / 2, 256, 0, stream>>>(q, ksum, khi_g, klo_g, vthi_g, vtlo_g,
                                             cdf, sim, pvt, kbmax, out);
}

// Round 10
// 201.559 us; speedup vs baseline: 1.9616x; 1.9616x over previous
//
#include <hip/hip_runtime.h>
#include <hip/hip_bf16.h>
#include <math.h>
#include <stdint.h>

#define B 2
#define H 16
#define L 2048
#define D 64
#define NB 32

typedef unsigned short u16;
typedef unsigned int u32;
typedef __attribute__((ext_vector_type(2))) unsigned int u32x2;
typedef __attribute__((ext_vector_type(4))) unsigned int u32x4;
typedef __attribute__((ext_vector_type(8))) short s16x8;
typedef __attribute__((ext_vector_type(4))) float f32x4;

union FragU { s16x8 v; u32 u[4]; };

__device__ __forceinline__ u32 pkbf(float a, float b) {
  __hip_bfloat162 h = __float22bfloat162_rn(make_float2(a, b));  // v_cvt_pk_bf16_f32
  union { __hip_bfloat162 h; u32 u; } cv; cv.h = h; return cv.u;
}
__device__ __forceinline__ float bf2f(u32 u16bits) {
  union { u32 u; float f; } c; c.u = u16bits << 16; return c.f;
}
// split float4 -> packed hi (u32x2) + lo (u32x2), RNE both levels
__device__ __forceinline__ void split4(float4 p, u32x2& hi, u32x2& lo) {
  u32 h01 = pkbf(p.x, p.y), h23 = pkbf(p.z, p.w);
  float rx = p.x - bf2f(h01 & 0xffffu);
  float ry = p.y - bf2f(h01 >> 16);
  float rz = p.z - bf2f(h23 & 0xffffu);
  float rw = p.w - bf2f(h23 >> 16);
  hi = (u32x2){h01, h23};
  lo = (u32x2){pkbf(rx, ry), pkbf(rz, rw)};
}
// XOR-swizzled byte offset in a [64][128B] tile: 2 lanes/bank (free) for the
// fixed-col/varying-row ds_read_b128 / 8B-store pattern (guide §6 G4).
__device__ __forceinline__ int swz(int row, int colb) {
  return (row << 7) + (colb ^ ((row & 7) << 4));
}

// ---------------------------------------------------------------------------
// k_prep: single pass over K (split + column sums fused), V transpose split.
// 16 B stores on all four bf16 planes. Per-(bh,j) max ||k_row||^2.
// ---------------------------------------------------------------------------
__global__ __launch_bounds__(256) void k_prep(const float* __restrict__ k,
                                              const float* __restrict__ v,
                                              float* __restrict__ ksum,
                                              u16* __restrict__ khi_g,
                                              u16* __restrict__ klo_g,
                                              u16* __restrict__ vthi_g,
                                              u16* __restrict__ vtlo_g,
                                              float* __restrict__ kbmax) {
  int blk = blockIdx.x, bh = blk >> 5, j = blk & 31, t = threadIdx.x;
  int lane = t & 63, w = t >> 6;
  __shared__ float vt[64 * 65];
  __shared__ float pk_[4][64];
  __shared__ unsigned bmaxS;
  if (t == 0) bmaxS = 0u;
  size_t base = (size_t)blk * 4096;

  int r0 = t >> 3;          // 0..31
  int c8 = (t & 7) * 8;     // 0..56
  float cs[8] = {0.f, 0.f, 0.f, 0.f, 0.f, 0.f, 0.f, 0.f};
  float rmax = 0.f;
#pragma unroll
  for (int it = 0; it < 2; ++it) {
    int r = r0 + 32 * it;
    const float* kp = k + base + r * 64 + c8;
    float4 f0 = *(const float4*)kp;
    float4 f1 = *(const float4*)(kp + 4);
    u32x2 h0, l0, h1, l1;
    split4(f0, h0, l0); split4(f1, h1, l1);
    *(u32x4*)(khi_g + base + r * 64 + c8) = (u32x4){h0[0], h0[1], h1[0], h1[1]};
    *(u32x4*)(klo_g + base + r * 64 + c8) = (u32x4){l0[0], l0[1], l1[0], l1[1]};
    cs[0] += f0.x; cs[1] += f0.y; cs[2] += f0.z; cs[3] += f0.w;
    cs[4] += f1.x; cs[5] += f1.y; cs[6] += f1.z; cs[7] += f1.w;
    float ssq = f0.x*f0.x + f0.y*f0.y + f0.z*f0.z + f0.w*f0.w
              + f1.x*f1.x + f1.y*f1.y + f1.z*f1.z + f1.w*f1.w;
    ssq += __shfl_xor(ssq, 1); ssq += __shfl_xor(ssq, 2); ssq += __shfl_xor(ssq, 4);
    if ((t & 7) == 0) rmax = fmaxf(rmax, ssq);
    const float* vp = v + base + r * 64 + c8;
    float4 g0 = *(const float4*)vp;
    float4 g1 = *(const float4*)(vp + 4);
    vt[(c8 + 0) * 65 + r] = g0.x;
    vt[(c8 + 1) * 65 + r] = g0.y;
    vt[(c8 + 2) * 65 + r] = g0.z;
    vt[(c8 + 3) * 65 + r] = g0.w;
    vt[(c8 + 4) * 65 + r] = g1.x;
    vt[(c8 + 5) * 65 + r] = g1.y;
    vt[(c8 + 6) * 65 + r] = g1.z;
    vt[(c8 + 7) * 65 + r] = g1.w;
  }
  if ((t & 7) == 0) atomicMax(&bmaxS, __float_as_uint(rmax));
  // column-sum reduce over r-groups: xor 8/16/32 keep lane&7 (the column group)
#pragma unroll
  for (int i = 0; i < 8; ++i) {
    cs[i] += __shfl_xor(cs[i], 8);
    cs[i] += __shfl_xor(cs[i], 16);
    cs[i] += __shfl_xor(cs[i], 32);
  }
  if (lane < 8) {
    *(float4*)&pk_[w][lane * 8]     = (float4){cs[0], cs[1], cs[2], cs[3]};
    *(float4*)&pk_[w][lane * 8 + 4] = (float4){cs[4], cs[5], cs[6], cs[7]};
  }
  __syncthreads();
  if (t < 64) ksum[(size_t)blk * 64 + t] = pk_[0][t] + pk_[1][t] + pk_[2][t] + pk_[3][t];
  if (t == 0) kbmax[blk] = __uint_as_float(bmaxS);
#pragma unroll
  for (int it = 0; it < 2; ++it) {
    int idx = t + 256 * it, d = idx >> 3, s8 = (idx & 7) * 8;
    const float* vr = &vt[d * 65 + s8];
    float4 f0 = {vr[0], vr[1], vr[2], vr[3]};
    float4 f1 = {vr[4], vr[5], vr[6], vr[7]};
    u32x2 h0, l0, h1, l1;
    split4(f0, h0, l0); split4(f1, h1, l1);
    size_t o = (size_t)bh * 131072 + (size_t)d * 2048 + j * 64 + s8;
    *(u32x4*)(vthi_g + o) = (u32x4){h0[0], h0[1], h1[0], h1[1]};
    *(u32x4*)(vtlo_g + o) = (u32x4){l0[0], l0[1], l1[0], l1[1]};
  }
}

// ---------------------------------------------------------------------------
// k_attn: round-1 body (2 q-blocks/WG, union-mask K sweep, cooperative loads,
// proven spill-free at launch_bounds(256,2)) + two local fixes:
//  (1) P tiles XOR-swizzled [64][128B] planes -> bank conflicts ~free
//  (2) P DOUBLE-BUFFERED -> ONE barrier per j in Pass B (WAR barrier gone;
//      iter i+2's write of buf is fenced by iter i+1's barrier).
// Occupancy axis intentionally abandoned: body needs ~200 regs (R3/R4/R8/R9
// all spilled at (256,3+)); 2 WGs/CU is the stable operating point.
// LDS map (bytes), total 65568 (2 WGs/CU at 160 KB):
//   P planes: qb 0/1 x buf 0/1 x {hi,lo}: qb*32768 + b*16384 + {0,8192}
//   overlay (dead before Pass B, all inside qb0 region 0..20480):
//     rbm u32[2*64*33] @0 (16896), lpart f32[4][128] @16896,
//     qm f32[2][64] @18944, MS @19456, linv @19968
//   flg @65536
// ---------------------------------------------------------------------------
__global__ __launch_bounds__(256, 2) void k_attn(
    const float* __restrict__ q,
    const float* __restrict__ ksum,
    const u16* __restrict__ khi_g, const u16* __restrict__ klo_g,
    const u16* __restrict__ vthi_g, const u16* __restrict__ vtlo_g,
    const float* __restrict__ cdfthreshd, const float* __restrict__ simthreshd1,
    const float* __restrict__ pvthreshd, const float* __restrict__ kbmax,
    float* __restrict__ out) {
  int blk0 = blockIdx.x;
  int blk = (blk0 & 7) * 64 + (blk0 >> 3);   // bijective: 512 % 8 == 0
  int bh = blk >> 4, ip = blk & 15, h = bh & (H - 1);
  int t = threadIdx.x, lane = t & 63, w = t >> 6;
  int m16 = lane & 15, quad = lane >> 4;

  __shared__ __align__(16) uint8_t smem[65568];
  u32*   rbm0  = (u32*)smem;                    // overlay: [2][64][33] keys
  float* lpart = (float*)(smem + 16896);        // [4][128]
  float* qmS   = (float*)(smem + 18944);        // [2][64]
  float* MSs   = (float*)(smem + 19456);        // [2][64]
  float* linvS = (float*)(smem + 19968);        // [2][64]
  int*   flg   = (int*)(smem + 65536);          // [0..1] pooled, [2..3] mw, [4..5] gm, [6] kmax2
#define PHB(qb, b) (smem + (qb) * 32768 + (b) * 16384)
#define PLB(qb, b) (smem + (qb) * 32768 + (b) * 16384 + 8192)

  const float* qg0 = q + ((size_t)bh * L + (size_t)(2 * ip) * 64) * D;
  const float* qg1 = qg0 + 64 * D;
  const u16* kh = khi_g + (size_t)bh * (L * D);
  const u16* kl = klo_g + (size_t)bh * (L * D);
  const u16* vh = vthi_g + (size_t)bh * (L * D);
  const u16* vl = vtlo_g + (size_t)bh * (L * D);

  // ---- Q B-fragments from global (f32 -> split, registers) ----
  s16x8 qhf[2][4][2], qlf[2][4][2];
#pragma unroll
  for (int qb = 0; qb < 2; ++qb) {
    const float* qgq = qb ? qg1 : qg0;
#pragma unroll
    for (int nt = 0; nt < 4; ++nt)
#pragma unroll
      for (int ks = 0; ks < 2; ++ks) {
        const float* p0 = qgq + (16 * nt + m16) * 64 + ks * 32 + quad * 8;
        float4 a = *(const float4*)p0;
        float4 b2 = *(const float4*)(p0 + 4);
        u32x2 ha, la, hb, lb;
        split4(a, ha, la); split4(b2, hb, lb);
        FragU fh, fl;
        fh.u[0] = ha[0]; fh.u[1] = ha[1]; fh.u[2] = hb[0]; fh.u[3] = hb[1];
        fl.u[0] = la[0]; fl.u[1] = la[1]; fl.u[2] = lb[0]; fl.u[3] = lb[1];
        qhf[qb][nt][ks] = fh.v; qlf[qb][nt][ks] = fl.v;
      }
  }
  for (int e = t; e < 2 * 64 * 33; e += 256)
    rbm0[e] = 0x7F800000u;   // +inf keys (rbm0, rbm1 contiguous)

  // ---- phase 1: qm per qb (w0,w2), kmax2 (w1) ----
  if (w == 0 || w == 2) {
    int qb = w >> 1;
    const float* qgq = qb ? qg1 : qg0;
    float s = 0.f;
    for (int r = 0; r < 64; ++r) s += qgq[r * 64 + lane];
    qmS[qb * 64 + lane] = s * (1.f / 64.f);
  }
  if (w == 1) {
    float m = (lane < 32) ? kbmax[bh * 32 + lane] : 0.f;
    for (int off = 16; off; off >>= 1) m = fmaxf(m, __shfl_xor(m, off, 32));
    if (lane == 0) ((float*)flg)[6] = m;
  }
  __syncthreads();

  // ---- phase 2: CDF keep (w0:qb0, w2:qb1); pooled cos + M (w1:qb0, w3:qb1) ----
  bool keepj = false;
  if ((w == 0 || w == 2) && lane < 32) {
    int qb = w >> 1, j = lane;
    const float* qmv = qmS + qb * 64;
    const float* ksp = ksum + (size_t)bh * NB * 64 + j * 64;
    float sv = 0.f;
    for (int d = 0; d < 64; ++d) sv += qmv[d] * ksp[d];
    sv *= (1.f / 64.f) * 0.125f;
    float mx = sv;
    for (int off = 16; off; off >>= 1) mx = fmaxf(mx, __shfl_xor(mx, off, 32));
    float p = expf(sv - mx);
    float sum = p;
    for (int off = 16; off; off >>= 1) sum += __shfl_xor(sum, off, 32);
    p /= sum;
    float excl = 0.f;
    for (int u = 0; u < 32; ++u) {
      float pu = __shfl(p, u, 32);
      if ((pu > p) || (pu == p && u < j)) excl += pu;
    }
    keepj = excl < cdfthreshd[h];
  }
  if (w == 1 || w == 3) {
    int qb = w >> 1, r = lane;
    const float* qgq = qb ? qg1 : qg0;
    const float* qmv = qmS + qb * 64;
    float kmax2 = ((float*)flg)[6];
    float dot = 0.f, qn2 = 0.f, qmn2 = 0.f;
    for (int d = 0; d < 64; ++d) {
      float a = qgq[r * 64 + d], b2 = qmv[d];
      dot += a * b2; qn2 += a * a; qmn2 += b2 * b2;
    }
    float cs = dot / (sqrtf(qn2) * sqrtf(qmn2) + 1e-6f);
    float su = cs;
    for (int off = 32; off; off >>= 1) su += __shfl_xor(su, off);
    if (lane == 0) flg[qb] = (su * (1.f / 64.f)) > simthreshd1[h];
    MSs[qb * 64 + r] = sqrtf(qn2 * kmax2) * 0.125f;  // M_r >= |s| (Cauchy-Schwarz)
  }
  __syncthreads();
  if ((w == 0 || w == 2) && lane < 32) {
    int qb = w >> 1;
    bool bit = keepj || !flg[qb] || (lane == 0);
    unsigned long long bal = __ballot(bit);
    if (lane == 0) flg[2 + qb] = (int)(u32)bal;
  }
  __syncthreads();
  u32 mw0 = (u32)flg[2], mw1 = (u32)flg[3];

  float Mq[2][4];
#pragma unroll
  for (int qb = 0; qb < 2; ++qb)
#pragma unroll
    for (int nt = 0; nt < 4; ++nt) Mq[qb][nt] = MSs[qb * 64 + 16 * nt + m16];

  // ---- Pass A: union sweep, one K load serves both q-blocks ----
  float lp[2][4] = {{0.f,0.f,0.f,0.f},{0.f,0.f,0.f,0.f}};
  {
    u32 mwU = mw0 | mw1;
    int j = (int)__builtin_ctz(mwU);
    u32 rm_ = mwU & (mwU - 1);
    s16x8 ka[2][2], kan[2][2];
    {
      const u16* kr0 = kh + (size_t)(j * 64 + 16 * w + m16) * 64 + quad * 8;
      const u16* kl0 = kl + (size_t)(j * 64 + 16 * w + m16) * 64 + quad * 8;
#pragma unroll
      for (int ks = 0; ks < 2; ++ks) {
        ka[ks][0] = *(const s16x8*)(kr0 + ks * 32);
        ka[ks][1] = *(const s16x8*)(kl0 + ks * 32);
      }
    }
    for (;;) {
      int nj = -1;
      if (rm_) {
        nj = (int)__builtin_ctz(rm_); rm_ &= rm_ - 1;
        const u16* nr = kh + (size_t)(nj * 64 + 16 * w + m16) * 64 + quad * 8;
        const u16* nl = kl + (size_t)(nj * 64 + 16 * w + m16) * 64 + quad * 8;
#pragma unroll
        for (int ks = 0; ks < 2; ++ks) {
          kan[ks][0] = *(const s16x8*)(nr + ks * 32);
          kan[ks][1] = *(const s16x8*)(nl + ks * 32);
        }
      }
#pragma unroll
      for (int qb = 0; qb < 2; ++qb) {
        u32 mm = qb ? mw1 : mw0;
        if (!((mm >> j) & 1u)) continue;
        f32x4 acc[4];
#pragma unroll
        for (int nt = 0; nt < 4; ++nt) acc[nt] = (f32x4){0.f, 0.f, 0.f, 0.f};
        __builtin_amdgcn_s_setprio(1);
#pragma unroll
        for (int ks = 0; ks < 2; ++ks)
#pragma unroll
          for (int nt = 0; nt < 4; ++nt) {
            acc[nt] = __builtin_amdgcn_mfma_f32_16x16x32_bf16(ka[ks][0], qhf[qb][nt][ks], acc[nt], 0, 0, 0);
            acc[nt] = __builtin_amdgcn_mfma_f32_16x16x32_bf16(ka[ks][1], qhf[qb][nt][ks], acc[nt], 0, 0, 0);
            acc[nt] = __builtin_amdgcn_mfma_f32_16x16x32_bf16(ka[ks][0], qlf[qb][nt][ks], acc[nt], 0, 0, 0);
          }
        __builtin_amdgcn_s_setprio(0);
#pragma unroll
        for (int nt = 0; nt < 4; ++nt) {
          float vmax = -1e30f;
#pragma unroll
          for (int reg = 0; reg < 4; ++reg) {
            float s = acc[nt][reg] * 0.125f - Mq[qb][nt];
            lp[qb][nt] += __expf(s);
            vmax = fmaxf(vmax, s);
          }
          vmax = fmaxf(vmax, __shfl_xor(vmax, 16));
          vmax = fmaxf(vmax, __shfl_xor(vmax, 32));
          if (quad == 0)
            atomicMin(rbm0 + qb * (64 * 33) + (16 * nt + m16) * 33 + j,
                      __float_as_uint(fmaxf(-vmax, 0.f)));
        }
      }
      if (nj < 0) break;
#pragma unroll
      for (int ks = 0; ks < 2; ++ks) { ka[ks][0] = kan[ks][0]; ka[ks][1] = kan[ks][1]; }
      j = nj;
    }
  }
#pragma unroll
  for (int qb = 0; qb < 2; ++qb)
#pragma unroll
    for (int nt = 0; nt < 4; ++nt) {
      float s = lp[qb][nt];
      s += __shfl_xor(s, 16); s += __shfl_xor(s, 32);
      if (quad == 0) lpart[w * 128 + qb * 64 + 16 * nt + m16] = s;
    }
  __syncthreads();
  if (t < 128) linvS[t] = 1.f / (lpart[t] + lpart[128 + t] + lpart[256 + t] + lpart[384 + t]);
  __syncthreads();

  // ---- PV gate: wave0 -> qb0, wave1 -> qb1 ----
  if (w < 2 && lane < 32) {
    u32 mm = w ? mw1 : mw0;
    bool keep = (mm >> lane) & 1u;
    if (keep && lane != 0) {
      float thr = pvthreshd[h] * 1e-3f;
      const float* lin = linvS + w * 64;
      const u32* rb = rbm0 + w * (64 * 33);
      float mp = 0.f;
      for (int r = 0; r < 64; ++r) {
        float key = __uint_as_float(rb[r * 33 + lane]);
        mp = fmaxf(mp, __expf(-key) * lin[r]);
      }
      keep = mp >= thr;
    }
    unsigned long long bal = __ballot(keep);
    if (lane == 0) flg[4 + w] = (int)(u32)bal;
  }
  __syncthreads();
  u32 gm0 = (u32)flg[4], gm1 = (u32)flg[5];

  // ---- Pass B: double-buffered P, ONE barrier per j ----
  float linq[2][4];
#pragma unroll
  for (int qb = 0; qb < 2; ++qb)
#pragma unroll
    for (int nt = 0; nt < 4; ++nt) linq[qb][nt] = linvS[qb * 64 + 16 * nt + m16];
  f32x4 oacc[2][4];
#pragma unroll
  for (int qb = 0; qb < 2; ++qb)
#pragma unroll
    for (int nt = 0; nt < 4; ++nt) oacc[qb][nt] = (f32x4){0.f, 0.f, 0.f, 0.f};
  __syncthreads();   // overlay (rbm/linv) reads complete before first P write

  {
    u32 gmU = gm0 | gm1;
    int j = -1;
    u32 g2 = gmU;
    int buf = 0;
    s16x8 ka[2][2];
    if (g2) {
      j = (int)__builtin_ctz(g2); g2 &= g2 - 1;
      const u16* kr0 = kh + (size_t)(j * 64 + 16 * w + m16) * 64 + quad * 8;
      const u16* kl0 = kl + (size_t)(j * 64 + 16 * w + m16) * 64 + quad * 8;
#pragma unroll
      for (int ks = 0; ks < 2; ++ks) {
        ka[ks][0] = *(const s16x8*)(kr0 + ks * 32);
        ka[ks][1] = *(const s16x8*)(kl0 + ks * 32);
      }
    }
    while (j >= 0) {
      int in0 = (gm0 >> j) & 1, in1 = (gm1 >> j) & 1;
      // V^T A-frags for current j (issued early, consumed after the barrier)
      s16x8 va[2][2];
      {
        const u16* vr0 = vh + (size_t)(16 * w + m16) * L + j * 64 + quad * 8;
        const u16* vl0 = vl + (size_t)(16 * w + m16) * L + j * 64 + quad * 8;
#pragma unroll
        for (int ks = 0; ks < 2; ++ks) {
          va[ks][0] = *(const s16x8*)(vr0 + ks * 32);
          va[ks][1] = *(const s16x8*)(vl0 + ks * 32);
        }
      }
      // S + P-write per q-block into P[buf] (no WAR barrier needed: dbuf)
      f32x4 acc[4];
#pragma unroll
      for (int qb = 0; qb < 2; ++qb) {
        if (!(qb ? in1 : in0)) continue;
#pragma unroll
        for (int nt = 0; nt < 4; ++nt) acc[nt] = (f32x4){0.f, 0.f, 0.f, 0.f};
        __builtin_amdgcn_s_setprio(1);
#pragma unroll
        for (int ks = 0; ks < 2; ++ks)
#pragma unroll
          for (int nt = 0; nt < 4; ++nt) {
            acc[nt] = __builtin_amdgcn_mfma_f32_16x16x32_bf16(ka[ks][0], qhf[qb][nt][ks], acc[nt], 0, 0, 0);
            acc[nt] = __builtin_amdgcn_mfma_f32_16x16x32_bf16(ka[ks][1], qhf[qb][nt][ks], acc[nt], 0, 0, 0);
            acc[nt] = __builtin_amdgcn_mfma_f32_16x16x32_bf16(ka[ks][0], qlf[qb][nt][ks], acc[nt], 0, 0, 0);
          }
        __builtin_amdgcn_s_setprio(0);
#pragma unroll
        for (int nt = 0; nt < 4; ++nt) {
          float4 pv;
          pv.x = __expf(acc[nt][0] * 0.125f - Mq[qb][nt]) * linq[qb][nt];
          pv.y = __expf(acc[nt][1] * 0.125f - Mq[qb][nt]) * linq[qb][nt];
          pv.z = __expf(acc[nt][2] * 0.125f - Mq[qb][nt]) * linq[qb][nt];
          pv.w = __expf(acc[nt][3] * 0.125f - Mq[qb][nt]) * linq[qb][nt];
          u32x2 hi, lo; split4(pv, hi, lo);
          int off = swz(16 * nt + m16, 32 * w + 8 * quad);
          *(u32x2*)(PHB(qb, buf) + off) = hi;
          *(u32x2*)(PLB(qb, buf) + off) = lo;
        }
      }
      // prefetch next K (ka fully consumed)
      int nj = -1;
      if (g2) {
        nj = (int)__builtin_ctz(g2); g2 &= g2 - 1;
        const u16* nr = kh + (size_t)(nj * 64 + 16 * w + m16) * 64 + quad * 8;
        const u16* nl = kl + (size_t)(nj * 64 + 16 * w + m16) * 64 + quad * 8;
#pragma unroll
        for (int ks = 0; ks < 2; ++ks) {
          ka[ks][0] = *(const s16x8*)(nr + ks * 32);
          ka[ks][1] = *(const s16x8*)(nl + ks * 32);
        }
      }
      __syncthreads();   // P[buf] complete (RAW); next iter writes buf^1
      // PV for both q-blocks (va shared)
#pragma unroll
      for (int qb = 0; qb < 2; ++qb) {
        if (!(qb ? in1 : in0)) continue;
        const uint8_t* ph_ = PHB(qb, buf);
        const uint8_t* pl_ = PLB(qb, buf);
#pragma unroll
        for (int ks = 0; ks < 2; ++ks)
#pragma unroll
          for (int nt = 0; nt < 4; ++nt) {
            s16x8 pbh = *(const s16x8*)(ph_ + swz(16 * nt + m16, ks * 64 + quad * 16));
            s16x8 pbl = *(const s16x8*)(pl_ + swz(16 * nt + m16, ks * 64 + quad * 16));
            __builtin_amdgcn_s_setprio(1);
            oacc[qb][nt] = __builtin_amdgcn_mfma_f32_16x16x32_bf16(va[ks][0], pbh, oacc[qb][nt], 0, 0, 0);
            oacc[qb][nt] = __builtin_amdgcn_mfma_f32_16x16x32_bf16(va[ks][1], pbh, oacc[qb][nt], 0, 0, 0);
            oacc[qb][nt] = __builtin_amdgcn_mfma_f32_16x16x32_bf16(va[ks][0], pbl, oacc[qb][nt], 0, 0, 0);
            __builtin_amdgcn_s_setprio(0);
          }
      }
      buf ^= 1;
      j = nj;
    }
  }

  // ---- store O: lane holds q-row = 16nt+m16, d = 16w+4quad (f32x4) ----
#pragma unroll
  for (int qb = 0; qb < 2; ++qb) {
    float* ob = out + ((size_t)bh * L + (size_t)(2 * ip + qb) * 64) * D;
#pragma unroll
    for (int nt = 0; nt < 4; ++nt)
      *(f32x4*)(ob + (16 * nt + m16) * 64 + 16 * w + 4 * quad) = oacc[qb][nt];
  }
}

// ---------------------------------------------------------------------------
extern "C" void kernel_launch(void* const* d_in, const int* in_sizes, int n_in,
                              void* d_out, int out_size, void* d_ws, size_t ws_size,
                              hipStream_t stream) {
  (void)in_sizes; (void)n_in; (void)out_size; (void)ws_size;
  const float* q   = (const float*)d_in[0];
  const float* k   = (const float*)d_in[1];
  const float* v   = (const float*)d_in[2];
  const float* cdf = (const float*)d_in[3];
  const float* sim = (const float*)d_in[4];
  const float* pvt = (const float*)d_in[5];
  float* out = (float*)d_out;

  uint8_t* w8 = (uint8_t*)d_ws;
  float* ksum  = (float*)w8;                          // 1024*64 f (256 KB)
  float* kbmax = (float*)(w8 + 262144);               // 1024 f (4 KB)
  u16* khi_g  = (u16*)(w8 + 266240);                  // 4 planes x 8 MB
  u16* klo_g  = khi_g + (size_t)B * H * L * D;
  u16* vthi_g = klo_g + (size_t)B * H * L * D;
  u16* vtlo_g = vthi_g + (size_t)B * H * L * D;

  k_prep<<<B * H * NB, 256, 0, stream>>>(k, v, ksum, khi_g, klo_g, vthi_g, vtlo_g, kbmax);
  k_attn<<<B * H * NB / 2, 256, 0, stream>>>(q, ksum, khi_g, klo_g, vthi_g, vtlo_g,
                                             cdf, sim, pvt, kbmax, out);
}

// Round 11
// 197.850 us; speedup vs baseline: 1.9984x; 1.0187x over previous
//
#include <hip/hip_runtime.h>
#include <hip/hip_bf16.h>
#include <math.h>
#include <stdint.h>

#define B 2
#define H 16
#define L 2048
#define D 64
#define NB 32

typedef unsigned short u16;
typedef unsigned int u32;
typedef __attribute__((ext_vector_type(2))) unsigned int u32x2;
typedef __attribute__((ext_vector_type(4))) unsigned int u32x4;
typedef __attribute__((ext_vector_type(8))) short s16x8;
typedef __attribute__((ext_vector_type(4))) float f32x4;

union FragU { s16x8 v; u32 u[4]; };

#if defined(__has_builtin)
#if __has_builtin(__builtin_amdgcn_exp2f)
#define EXP2F __builtin_amdgcn_exp2f
#else
#define EXP2F exp2f
#endif
#else
#define EXP2F exp2f
#endif
#define LOG2E 1.4426950408889634f
#define C1SC 0.18033688011112042f   // 0.125 * log2(e)

__device__ __forceinline__ u32 pkbf(float a, float b) {
  __hip_bfloat162 h = __float22bfloat162_rn(make_float2(a, b));  // v_cvt_pk_bf16_f32
  union { __hip_bfloat162 h; u32 u; } cv; cv.h = h; return cv.u;
}
__device__ __forceinline__ float bf2f(u32 u16bits) {
  union { u32 u; float f; } c; c.u = u16bits << 16; return c.f;
}
// split float4 -> packed hi (u32x2) + lo (u32x2), RNE both levels
__device__ __forceinline__ void split4(float4 p, u32x2& hi, u32x2& lo) {
  u32 h01 = pkbf(p.x, p.y), h23 = pkbf(p.z, p.w);
  float rx = p.x - bf2f(h01 & 0xffffu);
  float ry = p.y - bf2f(h01 >> 16);
  float rz = p.z - bf2f(h23 & 0xffffu);
  float rw = p.w - bf2f(h23 >> 16);
  hi = (u32x2){h01, h23};
  lo = (u32x2){pkbf(rx, ry), pkbf(rz, rw)};
}
// XOR-swizzled byte offset in a [64][128B] tile: 2 lanes/bank (free) for the
// fixed-col/varying-row ds_read_b128 / 8B-store pattern (guide §6 G4).
__device__ __forceinline__ int swz(int row, int colb) {
  return (row << 7) + (colb ^ ((row & 7) << 4));
}

// ---------------------------------------------------------------------------
// k_prep: single pass over K (split + column sums fused), V transpose split.
// XCD-ALIGNED task map: task (bh,j) runs on XCD bh>>2 — the same XCD whose
// k_attn WGs consume bh's planes. Dirty plane lines persist in that L2
// across the launch -> k_attn first-touch becomes an L2 hit (was L3).
// ---------------------------------------------------------------------------
__global__ __launch_bounds__(256) void k_prep(const float* __restrict__ k,
                                              const float* __restrict__ v,
                                              float* __restrict__ ksum,
                                              u16* __restrict__ khi_g,
                                              u16* __restrict__ klo_g,
                                              u16* __restrict__ vthi_g,
                                              u16* __restrict__ vtlo_g,
                                              float* __restrict__ kbmax) {
  int blk0 = blockIdx.x, t = threadIdx.x;
  int xcd = blk0 & 7, sidx = blk0 >> 3;        // HW: XCD = blockIdx % 8
  int bh = xcd * 4 + (sidx >> 5), j = sidx & 31;
  int blk = bh * 32 + j;                       // bijective remap
  int lane = t & 63, w = t >> 6;
  __shared__ float vt[64 * 65];
  __shared__ float pk_[4][64];
  __shared__ unsigned bmaxS;
  if (t == 0) bmaxS = 0u;
  size_t base = (size_t)blk * 4096;

  int r0 = t >> 3;          // 0..31
  int c8 = (t & 7) * 8;     // 0..56
  float cs[8] = {0.f, 0.f, 0.f, 0.f, 0.f, 0.f, 0.f, 0.f};
  float rmax = 0.f;
#pragma unroll
  for (int it = 0; it < 2; ++it) {
    int r = r0 + 32 * it;
    const float* kp = k + base + r * 64 + c8;
    float4 f0 = *(const float4*)kp;
    float4 f1 = *(const float4*)(kp + 4);
    u32x2 h0, l0, h1, l1;
    split4(f0, h0, l0); split4(f1, h1, l1);
    *(u32x4*)(khi_g + base + r * 64 + c8) = (u32x4){h0[0], h0[1], h1[0], h1[1]};
    *(u32x4*)(klo_g + base + r * 64 + c8) = (u32x4){l0[0], l0[1], l1[0], l1[1]};
    cs[0] += f0.x; cs[1] += f0.y; cs[2] += f0.z; cs[3] += f0.w;
    cs[4] += f1.x; cs[5] += f1.y; cs[6] += f1.z; cs[7] += f1.w;
    float ssq = f0.x*f0.x + f0.y*f0.y + f0.z*f0.z + f0.w*f0.w
              + f1.x*f1.x + f1.y*f1.y + f1.z*f1.z + f1.w*f1.w;
    ssq += __shfl_xor(ssq, 1); ssq += __shfl_xor(ssq, 2); ssq += __shfl_xor(ssq, 4);
    if ((t & 7) == 0) rmax = fmaxf(rmax, ssq);
    const float* vp = v + base + r * 64 + c8;
    float4 g0 = *(const float4*)vp;
    float4 g1 = *(const float4*)(vp + 4);
    vt[(c8 + 0) * 65 + r] = g0.x;
    vt[(c8 + 1) * 65 + r] = g0.y;
    vt[(c8 + 2) * 65 + r] = g0.z;
    vt[(c8 + 3) * 65 + r] = g0.w;
    vt[(c8 + 4) * 65 + r] = g1.x;
    vt[(c8 + 5) * 65 + r] = g1.y;
    vt[(c8 + 6) * 65 + r] = g1.z;
    vt[(c8 + 7) * 65 + r] = g1.w;
  }
  if ((t & 7) == 0) atomicMax(&bmaxS, __float_as_uint(rmax));
  // column-sum reduce over r-groups: xor 8/16/32 keep lane&7 (the column group)
#pragma unroll
  for (int i = 0; i < 8; ++i) {
    cs[i] += __shfl_xor(cs[i], 8);
    cs[i] += __shfl_xor(cs[i], 16);
    cs[i] += __shfl_xor(cs[i], 32);
  }
  if (lane < 8) {
    *(float4*)&pk_[w][lane * 8]     = (float4){cs[0], cs[1], cs[2], cs[3]};
    *(float4*)&pk_[w][lane * 8 + 4] = (float4){cs[4], cs[5], cs[6], cs[7]};
  }
  __syncthreads();
  if (t < 64) ksum[(size_t)blk * 64 + t] = pk_[0][t] + pk_[1][t] + pk_[2][t] + pk_[3][t];
  if (t == 0) kbmax[blk] = __uint_as_float(bmaxS);
#pragma unroll
  for (int it = 0; it < 2; ++it) {
    int idx = t + 256 * it, d = idx >> 3, s8 = (idx & 7) * 8;
    const float* vr = &vt[d * 65 + s8];
    float4 f0 = {vr[0], vr[1], vr[2], vr[3]};
    float4 f1 = {vr[4], vr[5], vr[6], vr[7]};
    u32x2 h0, l0, h1, l1;
    split4(f0, h0, l0); split4(f1, h1, l1);
    size_t o = (size_t)bh * 131072 + (size_t)d * 2048 + j * 64 + s8;
    *(u32x4*)(vthi_g + o) = (u32x4){h0[0], h0[1], h1[0], h1[1]};
    *(u32x4*)(vtlo_g + o) = (u32x4){l0[0], l0[1], l1[0], l1[1]};
  }
}

// ---------------------------------------------------------------------------
// k_attn: round-10 body (best verified, 119.9 us) + three local changes:
//  (1) consumes XCD-aligned planes (k_prep remap) -> first-touch L2 hits
//  (2) exp2-domain softmax: exp(acc*0.125-Mq) == exp2(fma(acc,C1,-Mq*log2e));
//      rbm keys + PV gate consistently in log2 domain (same values, ~1ulp)
//  (3) nontemporal O stores (no L2 write-allocate pollution)
// LDS map unchanged (65568 B, 2 WGs/CU at launch_bounds(256,2)).
// ---------------------------------------------------------------------------
__global__ __launch_bounds__(256, 2) void k_attn(
    const float* __restrict__ q,
    const float* __restrict__ ksum,
    const u16* __restrict__ khi_g, const u16* __restrict__ klo_g,
    const u16* __restrict__ vthi_g, const u16* __restrict__ vtlo_g,
    const float* __restrict__ cdfthreshd, const float* __restrict__ simthreshd1,
    const float* __restrict__ pvthreshd, const float* __restrict__ kbmax,
    float* __restrict__ out) {
  int blk0 = blockIdx.x;
  int blk = (blk0 & 7) * 64 + (blk0 >> 3);   // bijective: 512 % 8 == 0
  int bh = blk >> 4, ip = blk & 15, h = bh & (H - 1);
  int t = threadIdx.x, lane = t & 63, w = t >> 6;
  int m16 = lane & 15, quad = lane >> 4;

  __shared__ __align__(16) uint8_t smem[65568];
  u32*   rbm0  = (u32*)smem;                    // overlay: [2][64][33] keys
  float* lpart = (float*)(smem + 16896);        // [4][128]
  float* qmS   = (float*)(smem + 18944);        // [2][64]
  float* MSs   = (float*)(smem + 19456);        // [2][64]
  float* linvS = (float*)(smem + 19968);        // [2][64]
  int*   flg   = (int*)(smem + 65536);          // [0..1] pooled, [2..3] mw, [4..5] gm, [6] kmax2
#define PHB(qb, b) (smem + (qb) * 32768 + (b) * 16384)
#define PLB(qb, b) (smem + (qb) * 32768 + (b) * 16384 + 8192)

  const float* qg0 = q + ((size_t)bh * L + (size_t)(2 * ip) * 64) * D;
  const float* qg1 = qg0 + 64 * D;
  const u16* kh = khi_g + (size_t)bh * (L * D);
  const u16* kl = klo_g + (size_t)bh * (L * D);
  const u16* vh = vthi_g + (size_t)bh * (L * D);
  const u16* vl = vtlo_g + (size_t)bh * (L * D);

  // ---- Q B-fragments from global (f32 -> split, registers) ----
  s16x8 qhf[2][4][2], qlf[2][4][2];
#pragma unroll
  for (int qb = 0; qb < 2; ++qb) {
    const float* qgq = qb ? qg1 : qg0;
#pragma unroll
    for (int nt = 0; nt < 4; ++nt)
#pragma unroll
      for (int ks = 0; ks < 2; ++ks) {
        const float* p0 = qgq + (16 * nt + m16) * 64 + ks * 32 + quad * 8;
        float4 a = *(const float4*)p0;
        float4 b2 = *(const float4*)(p0 + 4);
        u32x2 ha, la, hb, lb;
        split4(a, ha, la); split4(b2, hb, lb);
        FragU fh, fl;
        fh.u[0] = ha[0]; fh.u[1] = ha[1]; fh.u[2] = hb[0]; fh.u[3] = hb[1];
        fl.u[0] = la[0]; fl.u[1] = la[1]; fl.u[2] = lb[0]; fl.u[3] = lb[1];
        qhf[qb][nt][ks] = fh.v; qlf[qb][nt][ks] = fl.v;
      }
  }
  for (int e = t; e < 2 * 64 * 33; e += 256)
    rbm0[e] = 0x7F800000u;   // +inf keys (rbm0, rbm1 contiguous)

  // ---- phase 1: qm per qb (w0,w2), kmax2 (w1) ----
  if (w == 0 || w == 2) {
    int qb = w >> 1;
    const float* qgq = qb ? qg1 : qg0;
    float s = 0.f;
    for (int r = 0; r < 64; ++r) s += qgq[r * 64 + lane];
    qmS[qb * 64 + lane] = s * (1.f / 64.f);
  }
  if (w == 1) {
    float m = (lane < 32) ? kbmax[bh * 32 + lane] : 0.f;
    for (int off = 16; off; off >>= 1) m = fmaxf(m, __shfl_xor(m, off, 32));
    if (lane == 0) ((float*)flg)[6] = m;
  }
  __syncthreads();

  // ---- phase 2: CDF keep (w0:qb0, w2:qb1); pooled cos + M (w1:qb0, w3:qb1) ----
  bool keepj = false;
  if ((w == 0 || w == 2) && lane < 32) {
    int qb = w >> 1, j = lane;
    const float* qmv = qmS + qb * 64;
    const float* ksp = ksum + (size_t)bh * NB * 64 + j * 64;
    float sv = 0.f;
    for (int d = 0; d < 64; ++d) sv += qmv[d] * ksp[d];
    sv *= (1.f / 64.f) * 0.125f;
    float mx = sv;
    for (int off = 16; off; off >>= 1) mx = fmaxf(mx, __shfl_xor(mx, off, 32));
    float p = expf(sv - mx);
    float sum = p;
    for (int off = 16; off; off >>= 1) sum += __shfl_xor(sum, off, 32);
    p /= sum;
    float excl = 0.f;
    for (int u = 0; u < 32; ++u) {
      float pu = __shfl(p, u, 32);
      if ((pu > p) || (pu == p && u < j)) excl += pu;
    }
    keepj = excl < cdfthreshd[h];
  }
  if (w == 1 || w == 3) {
    int qb = w >> 1, r = lane;
    const float* qgq = qb ? qg1 : qg0;
    const float* qmv = qmS + qb * 64;
    float kmax2 = ((float*)flg)[6];
    float dot = 0.f, qn2 = 0.f, qmn2 = 0.f;
    for (int d = 0; d < 64; ++d) {
      float a = qgq[r * 64 + d], b2 = qmv[d];
      dot += a * b2; qn2 += a * a; qmn2 += b2 * b2;
    }
    float cs = dot / (sqrtf(qn2) * sqrtf(qmn2) + 1e-6f);
    float su = cs;
    for (int off = 32; off; off >>= 1) su += __shfl_xor(su, off);
    if (lane == 0) flg[qb] = (su * (1.f / 64.f)) > simthreshd1[h];
    MSs[qb * 64 + r] = sqrtf(qn2 * kmax2) * 0.125f;  // M_r >= |s| (Cauchy-Schwarz)
  }
  __syncthreads();
  if ((w == 0 || w == 2) && lane < 32) {
    int qb = w >> 1;
    bool bit = keepj || !flg[qb] || (lane == 0);
    unsigned long long bal = __ballot(bit);
    if (lane == 0) flg[2 + qb] = (int)(u32)bal;
  }
  __syncthreads();
  u32 mw0 = (u32)flg[2], mw1 = (u32)flg[3];

  // Mq in LOG2 domain (rbm keys / lse / gate all consistently log2)
  float Mq[2][4];
#pragma unroll
  for (int qb = 0; qb < 2; ++qb)
#pragma unroll
    for (int nt = 0; nt < 4; ++nt) Mq[qb][nt] = MSs[qb * 64 + 16 * nt + m16] * LOG2E;

  // ---- Pass A: union sweep, one K load serves both q-blocks ----
  float lp[2][4] = {{0.f,0.f,0.f,0.f},{0.f,0.f,0.f,0.f}};
  {
    u32 mwU = mw0 | mw1;
    int j = (int)__builtin_ctz(mwU);
    u32 rm_ = mwU & (mwU - 1);
    s16x8 ka[2][2], kan[2][2];
    {
      const u16* kr0 = kh + (size_t)(j * 64 + 16 * w + m16) * 64 + quad * 8;
      const u16* kl0 = kl + (size_t)(j * 64 + 16 * w + m16) * 64 + quad * 8;
#pragma unroll
      for (int ks = 0; ks < 2; ++ks) {
        ka[ks][0] = *(const s16x8*)(kr0 + ks * 32);
        ka[ks][1] = *(const s16x8*)(kl0 + ks * 32);
      }
    }
    for (;;) {
      int nj = -1;
      if (rm_) {
        nj = (int)__builtin_ctz(rm_); rm_ &= rm_ - 1;
        const u16* nr = kh + (size_t)(nj * 64 + 16 * w + m16) * 64 + quad * 8;
        const u16* nl = kl + (size_t)(nj * 64 + 16 * w + m16) * 64 + quad * 8;
#pragma unroll
        for (int ks = 0; ks < 2; ++ks) {
          kan[ks][0] = *(const s16x8*)(nr + ks * 32);
          kan[ks][1] = *(const s16x8*)(nl + ks * 32);
        }
      }
#pragma unroll
      for (int qb = 0; qb < 2; ++qb) {
        u32 mm = qb ? mw1 : mw0;
        if (!((mm >> j) & 1u)) continue;
        f32x4 acc[4];
#pragma unroll
        for (int nt = 0; nt < 4; ++nt) acc[nt] = (f32x4){0.f, 0.f, 0.f, 0.f};
        __builtin_amdgcn_s_setprio(1);
#pragma unroll
        for (int ks = 0; ks < 2; ++ks)
#pragma unroll
          for (int nt = 0; nt < 4; ++nt) {
            acc[nt] = __builtin_amdgcn_mfma_f32_16x16x32_bf16(ka[ks][0], qhf[qb][nt][ks], acc[nt], 0, 0, 0);
            acc[nt] = __builtin_amdgcn_mfma_f32_16x16x32_bf16(ka[ks][1], qhf[qb][nt][ks], acc[nt], 0, 0, 0);
            acc[nt] = __builtin_amdgcn_mfma_f32_16x16x32_bf16(ka[ks][0], qlf[qb][nt][ks], acc[nt], 0, 0, 0);
          }
        __builtin_amdgcn_s_setprio(0);
#pragma unroll
        for (int nt = 0; nt < 4; ++nt) {
          float vmax = -1e30f;
#pragma unroll
          for (int reg = 0; reg < 4; ++reg) {
            float s = fmaf(acc[nt][reg], C1SC, -Mq[qb][nt]);   // log2 domain
            lp[qb][nt] += EXP2F(s);
            vmax = fmaxf(vmax, s);
          }
          vmax = fmaxf(vmax, __shfl_xor(vmax, 16));
          vmax = fmaxf(vmax, __shfl_xor(vmax, 32));
          if (quad == 0)
            atomicMin(rbm0 + qb * (64 * 33) + (16 * nt + m16) * 33 + j,
                      __float_as_uint(fmaxf(-vmax, 0.f)));
        }
      }
      if (nj < 0) break;
#pragma unroll
      for (int ks = 0; ks < 2; ++ks) { ka[ks][0] = kan[ks][0]; ka[ks][1] = kan[ks][1]; }
      j = nj;
    }
  }
#pragma unroll
  for (int qb = 0; qb < 2; ++qb)
#pragma unroll
    for (int nt = 0; nt < 4; ++nt) {
      float s = lp[qb][nt];
      s += __shfl_xor(s, 16); s += __shfl_xor(s, 32);
      if (quad == 0) lpart[w * 128 + qb * 64 + 16 * nt + m16] = s;
    }
  __syncthreads();
  if (t < 128) linvS[t] = 1.f / (lpart[t] + lpart[128 + t] + lpart[256 + t] + lpart[384 + t]);
  __syncthreads();

  // ---- PV gate: wave0 -> qb0, wave1 -> qb1 (keys in log2 domain) ----
  if (w < 2 && lane < 32) {
    u32 mm = w ? mw1 : mw0;
    bool keep = (mm >> lane) & 1u;
    if (keep && lane != 0) {
      float thr = pvthreshd[h] * 1e-3f;
      const float* lin = linvS + w * 64;
      const u32* rb = rbm0 + w * (64 * 33);
      float mp = 0.f;
      for (int r = 0; r < 64; ++r) {
        float key = __uint_as_float(rb[r * 33 + lane]);
        mp = fmaxf(mp, EXP2F(-key) * lin[r]);
      }
      keep = mp >= thr;
    }
    unsigned long long bal = __ballot(keep);
    if (lane == 0) flg[4 + w] = (int)(u32)bal;
  }
  __syncthreads();
  u32 gm0 = (u32)flg[4], gm1 = (u32)flg[5];

  // ---- Pass B: double-buffered P, ONE barrier per j ----
  float linq[2][4];
#pragma unroll
  for (int qb = 0; qb < 2; ++qb)
#pragma unroll
    for (int nt = 0; nt < 4; ++nt) linq[qb][nt] = linvS[qb * 64 + 16 * nt + m16];
  f32x4 oacc[2][4];
#pragma unroll
  for (int qb = 0; qb < 2; ++qb)
#pragma unroll
    for (int nt = 0; nt < 4; ++nt) oacc[qb][nt] = (f32x4){0.f, 0.f, 0.f, 0.f};
  __syncthreads();   // overlay (rbm/linv) reads complete before first P write

  {
    u32 gmU = gm0 | gm1;
    int j = -1;
    u32 g2 = gmU;
    int buf = 0;
    s16x8 ka[2][2];
    if (g2) {
      j = (int)__builtin_ctz(g2); g2 &= g2 - 1;
      const u16* kr0 = kh + (size_t)(j * 64 + 16 * w + m16) * 64 + quad * 8;
      const u16* kl0 = kl + (size_t)(j * 64 + 16 * w + m16) * 64 + quad * 8;
#pragma unroll
      for (int ks = 0; ks < 2; ++ks) {
        ka[ks][0] = *(const s16x8*)(kr0 + ks * 32);
        ka[ks][1] = *(const s16x8*)(kl0 + ks * 32);
      }
    }
    while (j >= 0) {
      int in0 = (gm0 >> j) & 1, in1 = (gm1 >> j) & 1;
      // V^T A-frags for current j (issued early, consumed after the barrier)
      s16x8 va[2][2];
      {
        const u16* vr0 = vh + (size_t)(16 * w + m16) * L + j * 64 + quad * 8;
        const u16* vl0 = vl + (size_t)(16 * w + m16) * L + j * 64 + quad * 8;
#pragma unroll
        for (int ks = 0; ks < 2; ++ks) {
          va[ks][0] = *(const s16x8*)(vr0 + ks * 32);
          va[ks][1] = *(const s16x8*)(vl0 + ks * 32);
        }
      }
      // S + P-write per q-block into P[buf] (no WAR barrier needed: dbuf)
      f32x4 acc[4];
#pragma unroll
      for (int qb = 0; qb < 2; ++qb) {
        if (!(qb ? in1 : in0)) continue;
#pragma unroll
        for (int nt = 0; nt < 4; ++nt) acc[nt] = (f32x4){0.f, 0.f, 0.f, 0.f};
        __builtin_amdgcn_s_setprio(1);
#pragma unroll
        for (int ks = 0; ks < 2; ++ks)
#pragma unroll
          for (int nt = 0; nt < 4; ++nt) {
            acc[nt] = __builtin_amdgcn_mfma_f32_16x16x32_bf16(ka[ks][0], qhf[qb][nt][ks], acc[nt], 0, 0, 0);
            acc[nt] = __builtin_amdgcn_mfma_f32_16x16x32_bf16(ka[ks][1], qhf[qb][nt][ks], acc[nt], 0, 0, 0);
            acc[nt] = __builtin_amdgcn_mfma_f32_16x16x32_bf16(ka[ks][0], qlf[qb][nt][ks], acc[nt], 0, 0, 0);
          }
        __builtin_amdgcn_s_setprio(0);
#pragma unroll
        for (int nt = 0; nt < 4; ++nt) {
          float4 pv;
          pv.x = EXP2F(fmaf(acc[nt][0], C1SC, -Mq[qb][nt])) * linq[qb][nt];
          pv.y = EXP2F(fmaf(acc[nt][1], C1SC, -Mq[qb][nt])) * linq[qb][nt];
          pv.z = EXP2F(fmaf(acc[nt][2], C1SC, -Mq[qb][nt])) * linq[qb][nt];
          pv.w = EXP2F(fmaf(acc[nt][3], C1SC, -Mq[qb][nt])) * linq[qb][nt];
          u32x2 hi, lo; split4(pv, hi, lo);
          int off = swz(16 * nt + m16, 32 * w + 8 * quad);
          *(u32x2*)(PHB(qb, buf) + off) = hi;
          *(u32x2*)(PLB(qb, buf) + off) = lo;
        }
      }
      // prefetch next K (ka fully consumed)
      int nj = -1;
      if (g2) {
        nj = (int)__builtin_ctz(g2); g2 &= g2 - 1;
        const u16* nr = kh + (size_t)(nj * 64 + 16 * w + m16) * 64 + quad * 8;
        const u16* nl = kl + (size_t)(nj * 64 + 16 * w + m16) * 64 + quad * 8;
#pragma unroll
        for (int ks = 0; ks < 2; ++ks) {
          ka[ks][0] = *(const s16x8*)(nr + ks * 32);
          ka[ks][1] = *(const s16x8*)(nl + ks * 32);
        }
      }
      __syncthreads();   // P[buf] complete (RAW); next iter writes buf^1
      // PV for both q-blocks (va shared)
#pragma unroll
      for (int qb = 0; qb < 2; ++qb) {
        if (!(qb ? in1 : in0)) continue;
        const uint8_t* ph_ = PHB(qb, buf);
        const uint8_t* pl_ = PLB(qb, buf);
#pragma unroll
        for (int ks = 0; ks < 2; ++ks)
#pragma unroll
          for (int nt = 0; nt < 4; ++nt) {
            s16x8 pbh = *(const s16x8*)(ph_ + swz(16 * nt + m16, ks * 64 + quad * 16));
            s16x8 pbl = *(const s16x8*)(pl_ + swz(16 * nt + m16, ks * 64 + quad * 16));
            __builtin_amdgcn_s_setprio(1);
            oacc[qb][nt] = __builtin_amdgcn_mfma_f32_16x16x32_bf16(va[ks][0], pbh, oacc[qb][nt], 0, 0, 0);
            oacc[qb][nt] = __builtin_amdgcn_mfma_f32_16x16x32_bf16(va[ks][1], pbh, oacc[qb][nt], 0, 0, 0);
            oacc[qb][nt] = __builtin_amdgcn_mfma_f32_16x16x32_bf16(va[ks][0], pbl, oacc[qb][nt], 0, 0, 0);
            __builtin_amdgcn_s_setprio(0);
          }
      }
      buf ^= 1;
      j = nj;
    }
  }

  // ---- store O (nontemporal: no L2 write-allocate pollution) ----
#pragma unroll
  for (int qb = 0; qb < 2; ++qb) {
    float* ob = out + ((size_t)bh * L + (size_t)(2 * ip + qb) * 64) * D;
#pragma unroll
    for (int nt = 0; nt < 4; ++nt)
      __builtin_nontemporal_store(oacc[qb][nt],
          (f32x4*)(ob + (16 * nt + m16) * 64 + 16 * w + 4 * quad));
  }
}

// ---------------------------------------------------------------------------
extern "C" void kernel_launch(void* const* d_in, const int* in_sizes, int n_in,
                              void* d_out, int out_size, void* d_ws, size_t ws_size,
                              hipStream_t stream) {
  (void)in_sizes; (void)n_in; (void)out_size; (void)ws_size;
  const float* q   = (const float*)d_in[0];
  const float* k   = (const float*)d_in[1];
  const float* v   = (const float*)d_in[2];
  const float* cdf = (const float*)d_in[3];
  const float* sim = (const float*)d_in[4];
  const float* pvt = (const float*)d_in[5];
  float* out = (float*)d_out;

  uint8_t* w8 = (uint8_t*)d_ws;
  float* ksum  = (float*)w8;                          // 1024*64 f (256 KB)
  float* kbmax = (float*)(w8 + 262144);               // 1024 f (4 KB)
  u16* khi_g  = (u16*)(w8 + 266240);                  // 4 planes x 8 MB
  u16* klo_g  = khi_g + (size_t)B * H * L * D;
  u16* vthi_g = klo_g + (size_t)B * H * L * D;
  u16* vtlo_g = vthi_g + (size_t)B * H * L * D;

  k_prep<<<B * H * NB, 256, 0, stream>>>(k, v, ksum, khi_g, klo_g, vthi_g, vtlo_g, kbmax);
  k_attn<<<B * H * NB / 2, 256, 0, stream>>>(q, ksum, khi_g, klo_g, vthi_g, vtlo_g,
                                             cdf, sim, pvt, kbmax, out);
}